// Round 2
// baseline (645.168 us; speedup 1.0000x reference)
//
#include <hip/hip_runtime.h>

typedef unsigned short u16;
typedef unsigned int u32;
typedef __attribute__((ext_vector_type(8))) short short8;
typedef __attribute__((ext_vector_type(4))) float f32x4;

__device__ __forceinline__ float bf2f(u32 u) {
    union { u32 i; float f; } v; v.i = u << 16; return v.f;
}
__device__ __forceinline__ u16 f2bf(float f) {
    union { float f; u32 i; } v; v.f = f;
    u32 u = (v.i + 0x7fffu + ((v.i >> 16) & 1u)) >> 16;
    return (u16)u;
}

// ---------------- CSR build ----------------
__global__ void k_deg(const int* __restrict__ erow, int e, int* __restrict__ deg) {
    int i = blockIdx.x * blockDim.x + threadIdx.x;
    if (i < e) atomicAdd(&deg[erow[i]], 1);
}

__global__ void k_scan_a(const int* __restrict__ deg, int n, int* __restrict__ bsum) {
    __shared__ int lds[256];
    int b = blockIdx.x, t = threadIdx.x;
    int base = b * 1024;
    int s = 0;
    for (int i = t; i < 1024; i += 256) { int idx = base + i; if (idx < n) s += deg[idx]; }
    lds[t] = s; __syncthreads();
    for (int off = 128; off > 0; off >>= 1) { if (t < off) lds[t] += lds[t + off]; __syncthreads(); }
    if (t == 0) bsum[b] = lds[0];
}

__global__ void k_scan_b(const int* __restrict__ bsum, int nb, int* __restrict__ boff) {
    __shared__ int lds[256];
    int t = threadIdx.x;
    int v = (t < nb) ? bsum[t] : 0;
    lds[t] = v; __syncthreads();
    for (int off = 1; off < 256; off <<= 1) {
        int x = (t >= off) ? lds[t - off] : 0;
        __syncthreads();
        lds[t] += x;
        __syncthreads();
    }
    if (t < nb) boff[t] = lds[t] - v;
}

__global__ void k_scan_c(const int* __restrict__ deg, int n, const int* __restrict__ boff,
                         int* __restrict__ row_ptr, float* __restrict__ inv_deg) {
    __shared__ int lds[256];
    int b = blockIdx.x, t = threadIdx.x;
    int base = b * 1024 + t * 4;
    int v0 = 0, v1 = 0, v2 = 0, v3 = 0;
    if (base + 0 < n) v0 = deg[base + 0];
    if (base + 1 < n) v1 = deg[base + 1];
    if (base + 2 < n) v2 = deg[base + 2];
    if (base + 3 < n) v3 = deg[base + 3];
    int s = v0 + v1 + v2 + v3;
    lds[t] = s; __syncthreads();
    for (int off = 1; off < 256; off <<= 1) {
        int x = (t >= off) ? lds[t - off] : 0;
        __syncthreads();
        lds[t] += x;
        __syncthreads();
    }
    int run = boff[b] + lds[t] - s;
    if (base + 0 < n) { row_ptr[base + 0] = run; inv_deg[base + 0] = v0 > 0 ? 1.f / v0 : 0.f; run += v0; }
    if (base + 1 < n) { row_ptr[base + 1] = run; inv_deg[base + 1] = v1 > 0 ? 1.f / v1 : 0.f; run += v1; }
    if (base + 2 < n) { row_ptr[base + 2] = run; inv_deg[base + 2] = v2 > 0 ? 1.f / v2 : 0.f; run += v2; }
    if (base + 3 < n) { row_ptr[base + 3] = run; inv_deg[base + 3] = v3 > 0 ? 1.f / v3 : 0.f; run += v3; }
    if (b == gridDim.x - 1 && t == 255) row_ptr[n] = run;
}

__global__ void k_fill(const int* __restrict__ erow, const int* __restrict__ ecol, int e,
                       const int* __restrict__ row_ptr, int* __restrict__ cursor, int* __restrict__ cols) {
    int i = blockIdx.x * blockDim.x + threadIdx.x;
    if (i < e) {
        int r = erow[i];
        int p = row_ptr[r] + atomicAdd(&cursor[r], 1);
        cols[p] = ecol[i];
    }
}

// ---------------- SpMM layer1: fp32 X in; bf16 S, D, Xb out ----------------
__global__ void k_spmm_f32(const float2* __restrict__ X, const int* __restrict__ row_ptr,
                           const int* __restrict__ cols, const float* __restrict__ inv_deg,
                           u32* __restrict__ S2, u32* __restrict__ D2, u32* __restrict__ Xb, int n) {
    int w = (int)((blockIdx.x * blockDim.x + threadIdx.x) >> 6);
    if (w >= n) return;
    int lane = threadIdx.x & 63;
    int beg = row_ptr[w], end = row_ptr[w + 1];
    float a0 = 0.f, a1 = 0.f;
    for (int j0 = beg; j0 < end; j0 += 64) {
        int cnt = end - j0; if (cnt > 64) cnt = 64;
        int myc = (lane < cnt) ? cols[j0 + lane] : 0;
        for (int j = 0; j < cnt; ++j) {
            int c = __shfl(myc, j);
            float2 p = X[(size_t)c * 64 + lane];
            a0 += p.x;
            a1 += p.y;
        }
    }
    float s = inv_deg[w];
    a0 *= s; a1 *= s;
    float2 px = X[(size_t)w * 64 + lane];
    S2[(size_t)w * 64 + lane] = (u32)f2bf(a0) | ((u32)f2bf(a1) << 16);
    D2[(size_t)w * 64 + lane] = (u32)f2bf(px.x - a0) | ((u32)f2bf(px.y - a1) << 16);
    Xb[(size_t)w * 64 + lane] = (u32)f2bf(px.x) | ((u32)f2bf(px.y) << 16);
}

// ---------------- SpMM layer2: bf16 in (packed u32), bf16 S, D out ----------------
__global__ void k_spmm_bf16(const u32* __restrict__ X2, const int* __restrict__ row_ptr,
                            const int* __restrict__ cols, const float* __restrict__ inv_deg,
                            u32* __restrict__ S2, u32* __restrict__ D2, int n) {
    int w = (int)((blockIdx.x * blockDim.x + threadIdx.x) >> 6);
    if (w >= n) return;
    int lane = threadIdx.x & 63;
    int beg = row_ptr[w], end = row_ptr[w + 1];
    float a0 = 0.f, a1 = 0.f;
    for (int j0 = beg; j0 < end; j0 += 64) {
        int cnt = end - j0; if (cnt > 64) cnt = 64;
        int myc = (lane < cnt) ? cols[j0 + lane] : 0;
        for (int j = 0; j < cnt; ++j) {
            int c = __shfl(myc, j);
            u32 p = X2[(size_t)c * 64 + lane];
            a0 += bf2f(p & 0xffffu);
            a1 += bf2f(p >> 16);
        }
    }
    float s = inv_deg[w];
    a0 *= s; a1 *= s;
    u32 px = X2[(size_t)w * 64 + lane];
    float x0 = bf2f(px & 0xffffu), x1 = bf2f(px >> 16);
    S2[(size_t)w * 64 + lane] = (u32)f2bf(a0) | ((u32)f2bf(a1) << 16);
    D2[(size_t)w * 64 + lane] = (u32)f2bf(x0 - a0) | ((u32)f2bf(x1 - a1) << 16);
}

// ---------------- fused 3-group GEMM: U[:, t*64 .. t*64+63] = A_g @ W_g, K=128 ----------------
// group g = t / (Hout/64): g=0 -> S@Wl, g=1 -> D@Wh, g=2 -> X@Wm. W is fp32, 128 x Hout row-major.
__global__ __launch_bounds__(256)
void k_gemm(const u16* __restrict__ A0, const u16* __restrict__ A1, const u16* __restrict__ A2,
            const float* __restrict__ W0, const float* __restrict__ W1, const float* __restrict__ W2,
            u16* __restrict__ U, int n, int Hout) {
    const int ldu = 3 * Hout;
    int tpg = Hout >> 6;
    int t = blockIdx.y;
    int g = t / tpg;
    const u16* A = (g == 0) ? A0 : ((g == 1) ? A1 : A2);
    const float* W = (g == 0) ? W0 : ((g == 1) ? W1 : W2);
    int wcol0 = (t - g * tpg) * 64;
    int lane = threadIdx.x & 63;
    int wid = threadIdx.x >> 6;
    int m0 = blockIdx.x * 128 + wid * 32;
    int ln15 = lane & 15, lq = lane >> 4;

    // B fragments: lane holds n=ln15, k = c*32 + lq*8 + j  (m89-verified layout)
    short8 bfr[4][4];
    for (int ct = 0; ct < 4; ++ct) {
        int col = wcol0 + ct * 16 + ln15;
        for (int c = 0; c < 4; ++c) {
            short8 bv;
            int krow = c * 32 + lq * 8;
#pragma unroll
            for (int j = 0; j < 8; ++j) bv[j] = (short)f2bf(W[(krow + j) * Hout + col]);
            bfr[ct][c] = bv;
        }
    }

    f32x4 acc[2][4];
#pragma unroll
    for (int mt = 0; mt < 2; ++mt)
#pragma unroll
        for (int ct = 0; ct < 4; ++ct) { f32x4 z = {0.f, 0.f, 0.f, 0.f}; acc[mt][ct] = z; }

#pragma unroll
    for (int mt = 0; mt < 2; ++mt) {
        int row = m0 + mt * 16 + ln15;
        int ra = row < n ? row : n - 1;
        const short8* arow = (const short8*)(A + (size_t)ra * 128);
#pragma unroll
        for (int c = 0; c < 4; ++c) {
            short8 av = arow[c * 4 + lq];
#pragma unroll
            for (int ct = 0; ct < 4; ++ct)
                acc[mt][ct] = __builtin_amdgcn_mfma_f32_16x16x32_bf16(av, bfr[ct][c], acc[mt][ct], 0, 0, 0);
        }
    }

#pragma unroll
    for (int mt = 0; mt < 2; ++mt)
#pragma unroll
        for (int ct = 0; ct < 4; ++ct) {
            int col = t * 64 + ct * 16 + ln15;
#pragma unroll
            for (int r = 0; r < 4; ++r) {
                int row = m0 + mt * 16 + lq * 4 + r;
                if (row < n) U[(size_t)row * ldu + col] = f2bf(acc[mt][ct][r]);
            }
        }
}

// ---------------- combine layer 1 (H=128): attention mix + outer relu -> fea (bf16) ----------------
__global__ void k_combine128(const u16* __restrict__ U, const float2* __restrict__ vl,
                             const float2* __restrict__ vh, const float2* __restrict__ vm,
                             const float* __restrict__ att, int n, u32* __restrict__ fea) {
    int w = (int)((blockIdx.x * blockDim.x + threadIdx.x) >> 6);
    if (w >= n) return;
    int lane = threadIdx.x & 63;
    const u32* ur = (const u32*)(U + (size_t)w * 384);
    u32 pl = ur[lane], ph = ur[64 + lane], pm = ur[128 + lane];
    float ol0 = fmaxf(bf2f(pl & 0xffffu), 0.f), ol1 = fmaxf(bf2f(pl >> 16), 0.f);
    float oh0 = fmaxf(bf2f(ph & 0xffffu), 0.f), oh1 = fmaxf(bf2f(ph >> 16), 0.f);
    float om0 = fmaxf(bf2f(pm & 0xffffu), 0.f), om1 = fmaxf(bf2f(pm >> 16), 0.f);
    float2 ql = vl[lane], qh = vh[lane], qm = vm[lane];
    float d0 = ol0 * ql.x + ol1 * ql.y;
    float d1 = oh0 * qh.x + oh1 * qh.y;
    float d2 = om0 * qm.x + om1 * qm.y;
#pragma unroll
    for (int off = 32; off > 0; off >>= 1) {
        d0 += __shfl_xor(d0, off);
        d1 += __shfl_xor(d1, off);
        d2 += __shfl_xor(d2, off);
    }
    float s0 = 1.f / (1.f + __expf(-d0));
    float s1 = 1.f / (1.f + __expf(-d1));
    float s2 = 1.f / (1.f + __expf(-d2));
    float a0 = (s0 * att[0] + s1 * att[3] + s2 * att[6]) * (1.f / 3.f);
    float a1 = (s0 * att[1] + s1 * att[4] + s2 * att[7]) * (1.f / 3.f);
    float a2 = (s0 * att[2] + s1 * att[5] + s2 * att[8]) * (1.f / 3.f);
    float mx = fmaxf(a0, fmaxf(a1, a2));
    float e0 = __expf(a0 - mx), e1 = __expf(a1 - mx), e2 = __expf(a2 - mx);
    float inv = 3.f / (e0 + e1 + e2);
    float w0 = e0 * inv, w1 = e1 * inv, w2 = e2 * inv;
    float r0 = fmaxf(w0 * ol0 + w1 * oh0 + w2 * om0, 0.f);
    float r1 = fmaxf(w0 * ol1 + w1 * oh1 + w2 * om1, 0.f);
    fea[(size_t)w * 64 + lane] = (u32)f2bf(r0) | ((u32)f2bf(r1) << 16);
}

// ---------------- combine layer 2 (C=64): attention mix -> out (fp32), no relu ----------------
__global__ void k_combine64(const u16* __restrict__ U, const float* __restrict__ vl,
                            const float* __restrict__ vh, const float* __restrict__ vm,
                            const float* __restrict__ att, int n, float* __restrict__ out) {
    int w = (int)((blockIdx.x * blockDim.x + threadIdx.x) >> 6);
    if (w >= n) return;
    int lane = threadIdx.x & 63;
    const u16* ur = U + (size_t)w * 192;
    float ol = fmaxf(bf2f(ur[lane]), 0.f);
    float oh = fmaxf(bf2f(ur[64 + lane]), 0.f);
    float om = fmaxf(bf2f(ur[128 + lane]), 0.f);
    float d0 = ol * vl[lane];
    float d1 = oh * vh[lane];
    float d2 = om * vm[lane];
#pragma unroll
    for (int off = 32; off > 0; off >>= 1) {
        d0 += __shfl_xor(d0, off);
        d1 += __shfl_xor(d1, off);
        d2 += __shfl_xor(d2, off);
    }
    float s0 = 1.f / (1.f + __expf(-d0));
    float s1 = 1.f / (1.f + __expf(-d1));
    float s2 = 1.f / (1.f + __expf(-d2));
    float a0 = (s0 * att[0] + s1 * att[3] + s2 * att[6]) * (1.f / 3.f);
    float a1 = (s0 * att[1] + s1 * att[4] + s2 * att[7]) * (1.f / 3.f);
    float a2 = (s0 * att[2] + s1 * att[5] + s2 * att[8]) * (1.f / 3.f);
    float mx = fmaxf(a0, fmaxf(a1, a2));
    float e0 = __expf(a0 - mx), e1 = __expf(a1 - mx), e2 = __expf(a2 - mx);
    float inv = 3.f / (e0 + e1 + e2);
    float w0 = e0 * inv, w1 = e1 * inv, w2 = e2 * inv;
    out[(size_t)w * 64 + lane] = w0 * ol + w1 * oh + w2 * om;
}

extern "C" void kernel_launch(void* const* d_in, const int* in_sizes, int n_in,
                              void* d_out, int out_size, void* d_ws, size_t ws_size,
                              hipStream_t stream) {
    const int F = 128, H = 128, C = 64;
    int n = in_sizes[0] / F;
    int e = in_sizes[1] / 2;
    const float* x = (const float*)d_in[0];
    const int* ei = (const int*)d_in[1];
    const int* erow = ei;
    const int* ecol = ei + e;
    const float *Wl1 = (const float*)d_in[2], *Wh1 = (const float*)d_in[3], *Wm1 = (const float*)d_in[4];
    const float *vl1 = (const float*)d_in[5], *vh1 = (const float*)d_in[6], *vm1 = (const float*)d_in[7];
    const float* att1 = (const float*)d_in[8];
    const float *Wl2 = (const float*)d_in[9], *Wh2 = (const float*)d_in[10], *Wm2 = (const float*)d_in[11];
    const float *vl2 = (const float*)d_in[12], *vh2 = (const float*)d_in[13], *vm2 = (const float*)d_in[14];
    const float* att2 = (const float*)d_in[15];
    float* out = (float*)d_out;

    char* ws = (char*)d_ws;
    size_t off = 0;
    auto alloc = [&](size_t b) -> void* {
        void* p = ws + off;
        off = (off + b + 255) & ~(size_t)255;
        return p;
    };
    int* deg = (int*)alloc((size_t)n * 4);          // also reused as fill cursor
    int* row_ptr = (int*)alloc((size_t)(n + 1) * 4);
    float* inv_deg = (float*)alloc((size_t)n * 4);
    int* bsum = (int*)alloc(1024);
    int* boff = (int*)alloc(1024);
    int* cols = (int*)alloc((size_t)e * 4);
    u16* S = (u16*)alloc((size_t)n * 128 * 2);
    u16* D = (u16*)alloc((size_t)n * 128 * 2);
    u16* Xb = (u16*)alloc((size_t)n * 128 * 2);
    u16* fea = (u16*)alloc((size_t)n * 128 * 2);
    u16* U = (u16*)alloc((size_t)n * 384 * 2);
    (void)ws_size; (void)n_in; (void)out_size;

    const int tb = 256;
    hipMemsetAsync(deg, 0, (size_t)n * 4, stream);
    k_deg<<<(e + tb - 1) / tb, tb, 0, stream>>>(erow, e, deg);
    int nb = (n + 1023) / 1024;
    k_scan_a<<<nb, 256, 0, stream>>>(deg, n, bsum);
    k_scan_b<<<1, 256, 0, stream>>>(bsum, nb, boff);
    k_scan_c<<<nb, 256, 0, stream>>>(deg, n, boff, row_ptr, inv_deg);
    hipMemsetAsync(deg, 0, (size_t)n * 4, stream);
    k_fill<<<(e + tb - 1) / tb, tb, 0, stream>>>(erow, ecol, e, row_ptr, deg, cols);

    int wb = (n + 3) / 4;  // one wave per row, 4 waves/block

    // layer 1
    k_spmm_f32<<<wb, 256, 0, stream>>>((const float2*)x, row_ptr, cols, inv_deg,
                                       (u32*)S, (u32*)D, (u32*)Xb, n);
    dim3 g1((n + 127) / 128, 6);
    k_gemm<<<g1, 256, 0, stream>>>(S, D, Xb, Wl1, Wh1, Wm1, U, n, H);
    k_combine128<<<wb, 256, 0, stream>>>(U, (const float2*)vl1, (const float2*)vh1,
                                         (const float2*)vm1, att1, n, (u32*)fea);

    // layer 2
    k_spmm_bf16<<<wb, 256, 0, stream>>>((const u32*)fea, row_ptr, cols, inv_deg, (u32*)S, (u32*)D, n);
    dim3 g2((n + 127) / 128, 3);
    k_gemm<<<g2, 256, 0, stream>>>(S, D, fea, Wl2, Wh2, Wm2, U, n, C);
    k_combine64<<<wb, 256, 0, stream>>>(U, vl2, vh2, vm2, att2, n, out);
}

// Round 3
// 549.494 us; speedup vs baseline: 1.1741x; 1.1741x over previous
//
#include <hip/hip_runtime.h>

typedef unsigned short u16;
typedef unsigned int u32;
typedef __attribute__((ext_vector_type(8))) short short8;
typedef __attribute__((ext_vector_type(4))) float f32x4;

__device__ __forceinline__ float bf2f(u32 u) {
    union { u32 i; float f; } v; v.i = u << 16; return v.f;
}
__device__ __forceinline__ u16 f2bf(float f) {
    union { float f; u32 i; } v; v.f = f;
    u32 u = (v.i + 0x7fffu + ((v.i >> 16) & 1u)) >> 16;
    return (u16)u;
}

// ---------------- cast x (fp32) -> Xb (packed bf16 pairs) ----------------
__global__ void k_cast(const float4* __restrict__ X, u32* __restrict__ Xb, long total4) {
    long i = (long)blockIdx.x * blockDim.x + threadIdx.x;
    long stride = (long)gridDim.x * blockDim.x;
    for (; i < total4; i += stride) {
        float4 p = X[i];
        Xb[i * 2 + 0] = (u32)f2bf(p.x) | ((u32)f2bf(p.y) << 16);
        Xb[i * 2 + 1] = (u32)f2bf(p.z) | ((u32)f2bf(p.w) << 16);
    }
}

// ---------------- CSR build ----------------
__global__ void k_deg(const int* __restrict__ erow, int e, int* __restrict__ deg) {
    int i = blockIdx.x * blockDim.x + threadIdx.x;
    if (i < e) atomicAdd(&deg[erow[i]], 1);
}

__global__ void k_scan_a(const int* __restrict__ deg, int n, int* __restrict__ bsum) {
    __shared__ int lds[256];
    int b = blockIdx.x, t = threadIdx.x;
    int base = b * 1024;
    int s = 0;
    for (int i = t; i < 1024; i += 256) { int idx = base + i; if (idx < n) s += deg[idx]; }
    lds[t] = s; __syncthreads();
    for (int off = 128; off > 0; off >>= 1) { if (t < off) lds[t] += lds[t + off]; __syncthreads(); }
    if (t == 0) bsum[b] = lds[0];
}

__global__ void k_scan_b(const int* __restrict__ bsum, int nb, int* __restrict__ boff) {
    __shared__ int lds[256];
    int t = threadIdx.x;
    int v = (t < nb) ? bsum[t] : 0;
    lds[t] = v; __syncthreads();
    for (int off = 1; off < 256; off <<= 1) {
        int x = (t >= off) ? lds[t - off] : 0;
        __syncthreads();
        lds[t] += x;
        __syncthreads();
    }
    if (t < nb) boff[t] = lds[t] - v;
}

__global__ void k_scan_c(const int* __restrict__ deg, int n, const int* __restrict__ boff,
                         int* __restrict__ row_ptr, float* __restrict__ inv_deg) {
    __shared__ int lds[256];
    int b = blockIdx.x, t = threadIdx.x;
    int base = b * 1024 + t * 4;
    int v0 = 0, v1 = 0, v2 = 0, v3 = 0;
    if (base + 0 < n) v0 = deg[base + 0];
    if (base + 1 < n) v1 = deg[base + 1];
    if (base + 2 < n) v2 = deg[base + 2];
    if (base + 3 < n) v3 = deg[base + 3];
    int s = v0 + v1 + v2 + v3;
    lds[t] = s; __syncthreads();
    for (int off = 1; off < 256; off <<= 1) {
        int x = (t >= off) ? lds[t - off] : 0;
        __syncthreads();
        lds[t] += x;
        __syncthreads();
    }
    int run = boff[b] + lds[t] - s;
    if (base + 0 < n) { row_ptr[base + 0] = run; inv_deg[base + 0] = v0 > 0 ? 1.f / v0 : 0.f; run += v0; }
    if (base + 1 < n) { row_ptr[base + 1] = run; inv_deg[base + 1] = v1 > 0 ? 1.f / v1 : 0.f; run += v1; }
    if (base + 2 < n) { row_ptr[base + 2] = run; inv_deg[base + 2] = v2 > 0 ? 1.f / v2 : 0.f; run += v2; }
    if (base + 3 < n) { row_ptr[base + 3] = run; inv_deg[base + 3] = v3 > 0 ? 1.f / v3 : 0.f; run += v3; }
    if (b == gridDim.x - 1 && t == 255) row_ptr[n] = run;
}

__global__ void k_fill(const int* __restrict__ erow, const int* __restrict__ ecol, int e,
                       const int* __restrict__ row_ptr, int* __restrict__ cursor, int* __restrict__ cols) {
    int i = blockIdx.x * blockDim.x + threadIdx.x;
    if (i < e) {
        int r = erow[i];
        int p = row_ptr[r] + atomicAdd(&cursor[r], 1);
        cols[p] = ecol[i];
    }
}

// ---------------- SpMM: bf16 X in (packed u32), bf16 S, D out; 4x unrolled gather ----------------
__global__ void k_spmm(const u32* __restrict__ X2, const int* __restrict__ row_ptr,
                       const int* __restrict__ cols, const float* __restrict__ inv_deg,
                       u32* __restrict__ S2, u32* __restrict__ D2, int n) {
    int w = (int)((blockIdx.x * blockDim.x + threadIdx.x) >> 6);
    if (w >= n) return;
    int lane = threadIdx.x & 63;
    int beg = row_ptr[w], end = row_ptr[w + 1];
    float a0 = 0.f, a1 = 0.f;
    for (int j0 = beg; j0 < end; j0 += 64) {
        int cnt = end - j0; if (cnt > 64) cnt = 64;
        int myc = (lane < cnt) ? cols[j0 + lane] : 0;
        int j = 0;
        for (; j + 4 <= cnt; j += 4) {
            int c0 = __shfl(myc, j + 0);
            int c1 = __shfl(myc, j + 1);
            int c2 = __shfl(myc, j + 2);
            int c3 = __shfl(myc, j + 3);
            u32 p0 = X2[(size_t)c0 * 64 + lane];
            u32 p1 = X2[(size_t)c1 * 64 + lane];
            u32 p2 = X2[(size_t)c2 * 64 + lane];
            u32 p3 = X2[(size_t)c3 * 64 + lane];
            a0 += bf2f(p0 & 0xffffu) + bf2f(p1 & 0xffffu) + bf2f(p2 & 0xffffu) + bf2f(p3 & 0xffffu);
            a1 += bf2f(p0 >> 16) + bf2f(p1 >> 16) + bf2f(p2 >> 16) + bf2f(p3 >> 16);
        }
        for (; j < cnt; ++j) {
            int c = __shfl(myc, j);
            u32 p = X2[(size_t)c * 64 + lane];
            a0 += bf2f(p & 0xffffu);
            a1 += bf2f(p >> 16);
        }
    }
    float s = inv_deg[w];
    a0 *= s; a1 *= s;
    u32 px = X2[(size_t)w * 64 + lane];
    float x0 = bf2f(px & 0xffffu), x1 = bf2f(px >> 16);
    S2[(size_t)w * 64 + lane] = (u32)f2bf(a0) | ((u32)f2bf(a1) << 16);
    D2[(size_t)w * 64 + lane] = (u32)f2bf(x0 - a0) | ((u32)f2bf(x1 - a1) << 16);
}

// ---------------- fused 3-group GEMM: U[:, t*64 .. t*64+63] = A_g @ W_g, K=128 ----------------
// group g = t / (Hout/64): g=0 -> S@Wl, g=1 -> D@Wh, g=2 -> X@Wm. W is fp32, 128 x Hout row-major.
__global__ __launch_bounds__(256)
void k_gemm(const u16* __restrict__ A0, const u16* __restrict__ A1, const u16* __restrict__ A2,
            const float* __restrict__ W0, const float* __restrict__ W1, const float* __restrict__ W2,
            u16* __restrict__ U, int n, int Hout) {
    const int ldu = 3 * Hout;
    int tpg = Hout >> 6;
    int t = blockIdx.y;
    int g = t / tpg;
    const u16* A = (g == 0) ? A0 : ((g == 1) ? A1 : A2);
    const float* W = (g == 0) ? W0 : ((g == 1) ? W1 : W2);
    int wcol0 = (t - g * tpg) * 64;
    int lane = threadIdx.x & 63;
    int wid = threadIdx.x >> 6;
    int m0 = blockIdx.x * 128 + wid * 32;
    int ln15 = lane & 15, lq = lane >> 4;

    // B fragments: lane holds n=ln15, k = c*32 + lq*8 + j  (m89-verified layout)
    short8 bfr[4][4];
    for (int ct = 0; ct < 4; ++ct) {
        int col = wcol0 + ct * 16 + ln15;
        for (int c = 0; c < 4; ++c) {
            short8 bv;
            int krow = c * 32 + lq * 8;
#pragma unroll
            for (int j = 0; j < 8; ++j) bv[j] = (short)f2bf(W[(krow + j) * Hout + col]);
            bfr[ct][c] = bv;
        }
    }

    f32x4 acc[2][4];
#pragma unroll
    for (int mt = 0; mt < 2; ++mt)
#pragma unroll
        for (int ct = 0; ct < 4; ++ct) { f32x4 z = {0.f, 0.f, 0.f, 0.f}; acc[mt][ct] = z; }

#pragma unroll
    for (int mt = 0; mt < 2; ++mt) {
        int row = m0 + mt * 16 + ln15;
        int ra = row < n ? row : n - 1;
        const short8* arow = (const short8*)(A + (size_t)ra * 128);
#pragma unroll
        for (int c = 0; c < 4; ++c) {
            short8 av = arow[c * 4 + lq];
#pragma unroll
            for (int ct = 0; ct < 4; ++ct)
                acc[mt][ct] = __builtin_amdgcn_mfma_f32_16x16x32_bf16(av, bfr[ct][c], acc[mt][ct], 0, 0, 0);
        }
    }

#pragma unroll
    for (int mt = 0; mt < 2; ++mt)
#pragma unroll
        for (int ct = 0; ct < 4; ++ct) {
            int col = t * 64 + ct * 16 + ln15;
#pragma unroll
            for (int r = 0; r < 4; ++r) {
                int row = m0 + mt * 16 + lq * 4 + r;
                if (row < n) U[(size_t)row * ldu + col] = f2bf(acc[mt][ct][r]);
            }
        }
}

// ---------------- combine layer 1 (H=128): attention mix + outer relu -> fea (bf16) ----------------
__global__ void k_combine128(const u16* __restrict__ U, const float2* __restrict__ vl,
                             const float2* __restrict__ vh, const float2* __restrict__ vm,
                             const float* __restrict__ att, int n, u32* __restrict__ fea) {
    int w = (int)((blockIdx.x * blockDim.x + threadIdx.x) >> 6);
    if (w >= n) return;
    int lane = threadIdx.x & 63;
    const u32* ur = (const u32*)(U + (size_t)w * 384);
    u32 pl = ur[lane], ph = ur[64 + lane], pm = ur[128 + lane];
    float ol0 = fmaxf(bf2f(pl & 0xffffu), 0.f), ol1 = fmaxf(bf2f(pl >> 16), 0.f);
    float oh0 = fmaxf(bf2f(ph & 0xffffu), 0.f), oh1 = fmaxf(bf2f(ph >> 16), 0.f);
    float om0 = fmaxf(bf2f(pm & 0xffffu), 0.f), om1 = fmaxf(bf2f(pm >> 16), 0.f);
    float2 ql = vl[lane], qh = vh[lane], qm = vm[lane];
    float d0 = ol0 * ql.x + ol1 * ql.y;
    float d1 = oh0 * qh.x + oh1 * qh.y;
    float d2 = om0 * qm.x + om1 * qm.y;
#pragma unroll
    for (int off = 32; off > 0; off >>= 1) {
        d0 += __shfl_xor(d0, off);
        d1 += __shfl_xor(d1, off);
        d2 += __shfl_xor(d2, off);
    }
    float s0 = 1.f / (1.f + __expf(-d0));
    float s1 = 1.f / (1.f + __expf(-d1));
    float s2 = 1.f / (1.f + __expf(-d2));
    float a0 = (s0 * att[0] + s1 * att[3] + s2 * att[6]) * (1.f / 3.f);
    float a1 = (s0 * att[1] + s1 * att[4] + s2 * att[7]) * (1.f / 3.f);
    float a2 = (s0 * att[2] + s1 * att[5] + s2 * att[8]) * (1.f / 3.f);
    float mx = fmaxf(a0, fmaxf(a1, a2));
    float e0 = __expf(a0 - mx), e1 = __expf(a1 - mx), e2 = __expf(a2 - mx);
    float inv = 3.f / (e0 + e1 + e2);
    float w0 = e0 * inv, w1 = e1 * inv, w2 = e2 * inv;
    float r0 = fmaxf(w0 * ol0 + w1 * oh0 + w2 * om0, 0.f);
    float r1 = fmaxf(w0 * ol1 + w1 * oh1 + w2 * om1, 0.f);
    fea[(size_t)w * 64 + lane] = (u32)f2bf(r0) | ((u32)f2bf(r1) << 16);
}

// ---------------- combine layer 2 (C=64): attention mix -> out (fp32), no relu ----------------
__global__ void k_combine64(const u16* __restrict__ U, const float* __restrict__ vl,
                            const float* __restrict__ vh, const float* __restrict__ vm,
                            const float* __restrict__ att, int n, float* __restrict__ out) {
    int w = (int)((blockIdx.x * blockDim.x + threadIdx.x) >> 6);
    if (w >= n) return;
    int lane = threadIdx.x & 63;
    const u16* ur = U + (size_t)w * 192;
    float ol = fmaxf(bf2f(ur[lane]), 0.f);
    float oh = fmaxf(bf2f(ur[64 + lane]), 0.f);
    float om = fmaxf(bf2f(ur[128 + lane]), 0.f);
    float d0 = ol * vl[lane];
    float d1 = oh * vh[lane];
    float d2 = om * vm[lane];
#pragma unroll
    for (int off = 32; off > 0; off >>= 1) {
        d0 += __shfl_xor(d0, off);
        d1 += __shfl_xor(d1, off);
        d2 += __shfl_xor(d2, off);
    }
    float s0 = 1.f / (1.f + __expf(-d0));
    float s1 = 1.f / (1.f + __expf(-d1));
    float s2 = 1.f / (1.f + __expf(-d2));
    float a0 = (s0 * att[0] + s1 * att[3] + s2 * att[6]) * (1.f / 3.f);
    float a1 = (s0 * att[1] + s1 * att[4] + s2 * att[7]) * (1.f / 3.f);
    float a2 = (s0 * att[2] + s1 * att[5] + s2 * att[8]) * (1.f / 3.f);
    float mx = fmaxf(a0, fmaxf(a1, a2));
    float e0 = __expf(a0 - mx), e1 = __expf(a1 - mx), e2 = __expf(a2 - mx);
    float inv = 3.f / (e0 + e1 + e2);
    float w0 = e0 * inv, w1 = e1 * inv, w2 = e2 * inv;
    out[(size_t)w * 64 + lane] = w0 * ol + w1 * oh + w2 * om;
}

extern "C" void kernel_launch(void* const* d_in, const int* in_sizes, int n_in,
                              void* d_out, int out_size, void* d_ws, size_t ws_size,
                              hipStream_t stream) {
    const int F = 128, H = 128, C = 64;
    int n = in_sizes[0] / F;
    int e = in_sizes[1] / 2;
    const float* x = (const float*)d_in[0];
    const int* ei = (const int*)d_in[1];
    const int* erow = ei;
    const int* ecol = ei + e;
    const float *Wl1 = (const float*)d_in[2], *Wh1 = (const float*)d_in[3], *Wm1 = (const float*)d_in[4];
    const float *vl1 = (const float*)d_in[5], *vh1 = (const float*)d_in[6], *vm1 = (const float*)d_in[7];
    const float* att1 = (const float*)d_in[8];
    const float *Wl2 = (const float*)d_in[9], *Wh2 = (const float*)d_in[10], *Wm2 = (const float*)d_in[11];
    const float *vl2 = (const float*)d_in[12], *vh2 = (const float*)d_in[13], *vm2 = (const float*)d_in[14];
    const float* att2 = (const float*)d_in[15];
    float* out = (float*)d_out;

    char* ws = (char*)d_ws;
    size_t off = 0;
    auto alloc = [&](size_t b) -> void* {
        void* p = ws + off;
        off = (off + b + 255) & ~(size_t)255;
        return p;
    };
    int* deg = (int*)alloc((size_t)n * 4);          // also reused as fill cursor
    int* row_ptr = (int*)alloc((size_t)(n + 1) * 4);
    float* inv_deg = (float*)alloc((size_t)n * 4);
    int* bsum = (int*)alloc(1024);
    int* boff = (int*)alloc(1024);
    int* cols = (int*)alloc((size_t)e * 4);
    u16* S = (u16*)alloc((size_t)n * 128 * 2);
    u16* D = (u16*)alloc((size_t)n * 128 * 2);
    u16* Xb = (u16*)alloc((size_t)n * 128 * 2);
    u16* fea = (u16*)alloc((size_t)n * 128 * 2);
    u16* U = (u16*)alloc((size_t)n * 384 * 2);
    (void)ws_size; (void)n_in; (void)out_size;

    const int tb = 256;
    // cast x -> bf16 (runs while CSR build proceeds on other CUs is not possible on one
    // stream; it's cheap: ~77 MB streamed)
    k_cast<<<2048, 256, 0, stream>>>((const float4*)x, (u32*)Xb, (long)n * 32);

    hipMemsetAsync(deg, 0, (size_t)n * 4, stream);
    k_deg<<<(e + tb - 1) / tb, tb, 0, stream>>>(erow, e, deg);
    int nb = (n + 1023) / 1024;
    k_scan_a<<<nb, 256, 0, stream>>>(deg, n, bsum);
    k_scan_b<<<1, 256, 0, stream>>>(bsum, nb, boff);
    k_scan_c<<<nb, 256, 0, stream>>>(deg, n, boff, row_ptr, inv_deg);
    hipMemsetAsync(deg, 0, (size_t)n * 4, stream);
    k_fill<<<(e + tb - 1) / tb, tb, 0, stream>>>(erow, ecol, e, row_ptr, deg, cols);

    int wb = (n + 3) / 4;  // one wave per row, 4 waves/block

    // layer 1
    k_spmm<<<wb, 256, 0, stream>>>((const u32*)Xb, row_ptr, cols, inv_deg, (u32*)S, (u32*)D, n);
    dim3 g1((n + 127) / 128, 6);
    k_gemm<<<g1, 256, 0, stream>>>(S, D, Xb, Wl1, Wh1, Wm1, U, n, H);
    k_combine128<<<wb, 256, 0, stream>>>(U, (const float2*)vl1, (const float2*)vh1,
                                         (const float2*)vm1, att1, n, (u32*)fea);

    // layer 2
    k_spmm<<<wb, 256, 0, stream>>>((const u32*)fea, row_ptr, cols, inv_deg, (u32*)S, (u32*)D, n);
    dim3 g2((n + 127) / 128, 3);
    k_gemm<<<g2, 256, 0, stream>>>(S, D, fea, Wl2, Wh2, Wm2, U, n, C);
    k_combine64<<<wb, 256, 0, stream>>>(U, vl2, vh2, vm2, att2, n, out);
}

// Round 4
// 545.543 us; speedup vs baseline: 1.1826x; 1.0072x over previous
//
#include <hip/hip_runtime.h>

typedef unsigned short u16;
typedef unsigned int u32;
typedef __attribute__((ext_vector_type(8))) short short8;
typedef __attribute__((ext_vector_type(4))) float f32x4;

__device__ __forceinline__ float bf2f(u32 u) {
    union { u32 i; float f; } v; v.i = u << 16; return v.f;
}
__device__ __forceinline__ u16 f2bf(float f) {
    union { float f; u32 i; } v; v.f = f;
    u32 u = (v.i + 0x7fffu + ((v.i >> 16) & 1u)) >> 16;
    return (u16)u;
}

// ---------------- cast x (fp32) -> Xb (packed bf16 pairs) ----------------
__global__ void k_cast(const float4* __restrict__ X, u32* __restrict__ Xb, long total4) {
    long i = (long)blockIdx.x * blockDim.x + threadIdx.x;
    long stride = (long)gridDim.x * blockDim.x;
    for (; i < total4; i += stride) {
        float4 p = X[i];
        Xb[i * 2 + 0] = (u32)f2bf(p.x) | ((u32)f2bf(p.y) << 16);
        Xb[i * 2 + 1] = (u32)f2bf(p.z) | ((u32)f2bf(p.w) << 16);
    }
}

// ---------------- prep weights: fp32 [128 x Hout] row-major -> bf16 [Hout x 128] col-major ----------------
__global__ void k_prepW(const float* __restrict__ W0, const float* __restrict__ W1,
                        const float* __restrict__ W2, const float* __restrict__ W3,
                        const float* __restrict__ W4, const float* __restrict__ W5,
                        u16* __restrict__ Wt1, u16* __restrict__ Wt2) {
    int m = blockIdx.y;
    const float* W = (m == 0) ? W0 : (m == 1) ? W1 : (m == 2) ? W2 : (m == 3) ? W3 : (m == 4) ? W4 : W5;
    int Hout = (m < 3) ? 128 : 64;
    u16* dst = (m < 3) ? (Wt1 + m * 128 * 128) : (Wt2 + (m - 3) * 64 * 128);
    int total = 128 * Hout;
    for (int idx = blockIdx.x * blockDim.x + threadIdx.x; idx < total; idx += gridDim.x * blockDim.x) {
        int k = idx / Hout, c = idx % Hout;
        dst[c * 128 + k] = f2bf(W[idx]);
    }
}

// ---------------- CSR build ----------------
__global__ void k_deg(const int* __restrict__ erow, int e, int* __restrict__ deg) {
    int i = blockIdx.x * blockDim.x + threadIdx.x;
    if (i < e) atomicAdd(&deg[erow[i]], 1);
}

__global__ void k_scan_a(const int* __restrict__ deg, int n, int* __restrict__ bsum) {
    __shared__ int lds[256];
    int b = blockIdx.x, t = threadIdx.x;
    int base = b * 1024;
    int s = 0;
    for (int i = t; i < 1024; i += 256) { int idx = base + i; if (idx < n) s += deg[idx]; }
    lds[t] = s; __syncthreads();
    for (int off = 128; off > 0; off >>= 1) { if (t < off) lds[t] += lds[t + off]; __syncthreads(); }
    if (t == 0) bsum[b] = lds[0];
}

__global__ void k_scan_b(const int* __restrict__ bsum, int nb, int* __restrict__ boff) {
    __shared__ int lds[256];
    int t = threadIdx.x;
    int v = (t < nb) ? bsum[t] : 0;
    lds[t] = v; __syncthreads();
    for (int off = 1; off < 256; off <<= 1) {
        int x = (t >= off) ? lds[t - off] : 0;
        __syncthreads();
        lds[t] += x;
        __syncthreads();
    }
    if (t < nb) boff[t] = lds[t] - v;
}

__global__ void k_scan_c(const int* __restrict__ deg, int n, const int* __restrict__ boff,
                         int* __restrict__ row_ptr, float* __restrict__ inv_deg) {
    __shared__ int lds[256];
    int b = blockIdx.x, t = threadIdx.x;
    int base = b * 1024 + t * 4;
    int v0 = 0, v1 = 0, v2 = 0, v3 = 0;
    if (base + 0 < n) v0 = deg[base + 0];
    if (base + 1 < n) v1 = deg[base + 1];
    if (base + 2 < n) v2 = deg[base + 2];
    if (base + 3 < n) v3 = deg[base + 3];
    int s = v0 + v1 + v2 + v3;
    lds[t] = s; __syncthreads();
    for (int off = 1; off < 256; off <<= 1) {
        int x = (t >= off) ? lds[t - off] : 0;
        __syncthreads();
        lds[t] += x;
        __syncthreads();
    }
    int run = boff[b] + lds[t] - s;
    if (base + 0 < n) { row_ptr[base + 0] = run; inv_deg[base + 0] = v0 > 0 ? 1.f / v0 : 0.f; run += v0; }
    if (base + 1 < n) { row_ptr[base + 1] = run; inv_deg[base + 1] = v1 > 0 ? 1.f / v1 : 0.f; run += v1; }
    if (base + 2 < n) { row_ptr[base + 2] = run; inv_deg[base + 2] = v2 > 0 ? 1.f / v2 : 0.f; run += v2; }
    if (base + 3 < n) { row_ptr[base + 3] = run; inv_deg[base + 3] = v3 > 0 ? 1.f / v3 : 0.f; run += v3; }
    if (b == gridDim.x - 1 && t == 255) row_ptr[n] = run;
}

__global__ void k_fill(const int* __restrict__ erow, const int* __restrict__ ecol, int e,
                       const int* __restrict__ row_ptr, int* __restrict__ cursor, int* __restrict__ cols) {
    int i = blockIdx.x * blockDim.x + threadIdx.x;
    if (i < e) {
        int r = erow[i];
        int p = row_ptr[r] + atomicAdd(&cursor[r], 1);
        cols[p] = ecol[i];
    }
}

// ---------------- SpMM: bf16 X in (packed u32), bf16 S, D out; 4x unrolled gather ----------------
__global__ void k_spmm(const u32* __restrict__ X2, const int* __restrict__ row_ptr,
                       const int* __restrict__ cols, const float* __restrict__ inv_deg,
                       u32* __restrict__ S2, u32* __restrict__ D2, int n) {
    int w = (int)((blockIdx.x * blockDim.x + threadIdx.x) >> 6);
    if (w >= n) return;
    int lane = threadIdx.x & 63;
    int beg = row_ptr[w], end = row_ptr[w + 1];
    float a0 = 0.f, a1 = 0.f;
    for (int j0 = beg; j0 < end; j0 += 64) {
        int cnt = end - j0; if (cnt > 64) cnt = 64;
        int myc = (lane < cnt) ? cols[j0 + lane] : 0;
        int j = 0;
        for (; j + 4 <= cnt; j += 4) {
            int c0 = __shfl(myc, j + 0);
            int c1 = __shfl(myc, j + 1);
            int c2 = __shfl(myc, j + 2);
            int c3 = __shfl(myc, j + 3);
            u32 p0 = X2[(size_t)c0 * 64 + lane];
            u32 p1 = X2[(size_t)c1 * 64 + lane];
            u32 p2 = X2[(size_t)c2 * 64 + lane];
            u32 p3 = X2[(size_t)c3 * 64 + lane];
            a0 += bf2f(p0 & 0xffffu) + bf2f(p1 & 0xffffu) + bf2f(p2 & 0xffffu) + bf2f(p3 & 0xffffu);
            a1 += bf2f(p0 >> 16) + bf2f(p1 >> 16) + bf2f(p2 >> 16) + bf2f(p3 >> 16);
        }
        for (; j < cnt; ++j) {
            int c = __shfl(myc, j);
            u32 p = X2[(size_t)c * 64 + lane];
            a0 += bf2f(p & 0xffffu);
            a1 += bf2f(p >> 16);
        }
    }
    float s = inv_deg[w];
    a0 *= s; a1 *= s;
    u32 px = X2[(size_t)w * 64 + lane];
    float x0 = bf2f(px & 0xffffu), x1 = bf2f(px >> 16);
    S2[(size_t)w * 64 + lane] = (u32)f2bf(a0) | ((u32)f2bf(a1) << 16);
    D2[(size_t)w * 64 + lane] = (u32)f2bf(x0 - a0) | ((u32)f2bf(x1 - a1) << 16);
}

// ---------------- fused GEMM + attention combine ----------------
// Block: 256 thr (4 waves), 32 rows. Tiles t (16 cols of U = [S@Wl | D@Wh | X@Wm]) are assigned
// round-robin: wave w owns tiles {w, w+4, ...}. Since tiles-per-group (Hout/16) is a multiple
// of 4, the (low, high, mlp) values for the same output col land in the SAME lane of the SAME
// wave -> register-local attention mix. Per-row logits need a cross-wave LDS reduction only.
template<int HOUT, bool L1>
__global__ __launch_bounds__(256)
void k_gemm_comb(const u16* __restrict__ A0, const u16* __restrict__ A1, const u16* __restrict__ A2,
                 const u16* __restrict__ Wt,   // bf16 [3][HOUT][128] col-major
                 const float* __restrict__ vl, const float* __restrict__ vh, const float* __restrict__ vm,
                 const float* __restrict__ att, int n,
                 u16* __restrict__ feaOut, float* __restrict__ fOut) {
    constexpr int KPG = HOUT / 64;   // col-slots per group per wave (2 for H=128, 1 for H=64)
    constexpr int NTw = 3 * KPG;     // tiles per wave
    int w = threadIdx.x >> 6, lane = threadIdx.x & 63;
    int ln15 = lane & 15, lq = lane >> 4;
    int m0 = blockIdx.x * 32;

    f32x4 acc[2][NTw];
#pragma unroll
    for (int mt = 0; mt < 2; ++mt)
#pragma unroll
        for (int k = 0; k < NTw; ++k) { f32x4 z = {0.f, 0.f, 0.f, 0.f}; acc[mt][k] = z; }

#pragma unroll
    for (int c = 0; c < 4; ++c) {
        short8 a[2][3];
#pragma unroll
        for (int mt = 0; mt < 2; ++mt) {
            int row = m0 + mt * 16 + ln15;
            if (row >= n) row = n - 1;
            size_t base = (size_t)row * 128 + c * 32 + lq * 8;
            a[mt][0] = *(const short8*)(A0 + base);
            a[mt][1] = *(const short8*)(A1 + base);
            a[mt][2] = *(const short8*)(A2 + base);
        }
#pragma unroll
        for (int k = 0; k < NTw; ++k) {
            int g = k / KPG, kk = k % KPG;
            int col = w * 16 + kk * 64 + ln15;
            short8 b = *(const short8*)(Wt + ((size_t)(g * HOUT + col)) * 128 + c * 32 + lq * 8);
#pragma unroll
            for (int mt = 0; mt < 2; ++mt)
                acc[mt][k] = __builtin_amdgcn_mfma_f32_16x16x32_bf16(a[mt][g], b, acc[mt][k], 0, 0, 0);
        }
    }

    // per-lane partial row-dots with v vectors
    float vval[NTw];
#pragma unroll
    for (int k = 0; k < NTw; ++k) {
        int g = k / KPG, kk = k % KPG;
        int col = w * 16 + kk * 64 + ln15;
        vval[k] = (g == 0 ? vl : (g == 1 ? vh : vm))[col];
    }
    float pd[3][2][4];
#pragma unroll
    for (int g = 0; g < 3; ++g)
#pragma unroll
        for (int mt = 0; mt < 2; ++mt)
#pragma unroll
            for (int r = 0; r < 4; ++r) pd[g][mt][r] = 0.f;
#pragma unroll
    for (int k = 0; k < NTw; ++k) {
        int g = k / KPG;
#pragma unroll
        for (int mt = 0; mt < 2; ++mt)
#pragma unroll
            for (int r = 0; r < 4; ++r)
                pd[g][mt][r] += fmaxf(acc[mt][k][r], 0.f) * vval[k];
    }
#pragma unroll
    for (int off = 1; off < 16; off <<= 1)
#pragma unroll
        for (int g = 0; g < 3; ++g)
#pragma unroll
            for (int mt = 0; mt < 2; ++mt)
#pragma unroll
                for (int r = 0; r < 4; ++r)
                    pd[g][mt][r] += __shfl_xor(pd[g][mt][r], off);

    __shared__ float part[4][3][32];
    __shared__ float wgt[32][3];
    if (ln15 == 0) {
#pragma unroll
        for (int g = 0; g < 3; ++g)
#pragma unroll
            for (int mt = 0; mt < 2; ++mt)
#pragma unroll
                for (int r = 0; r < 4; ++r)
                    part[w][g][mt * 16 + lq * 4 + r] = pd[g][mt][r];
    }
    __syncthreads();
    if (threadIdx.x < 32) {
        int row = threadIdx.x;
        float d0 = part[0][0][row] + part[1][0][row] + part[2][0][row] + part[3][0][row];
        float d1 = part[0][1][row] + part[1][1][row] + part[2][1][row] + part[3][1][row];
        float d2 = part[0][2][row] + part[1][2][row] + part[2][2][row] + part[3][2][row];
        float s0 = 1.f / (1.f + __expf(-d0));
        float s1 = 1.f / (1.f + __expf(-d1));
        float s2 = 1.f / (1.f + __expf(-d2));
        float a0 = (s0 * att[0] + s1 * att[3] + s2 * att[6]) * (1.f / 3.f);
        float a1 = (s0 * att[1] + s1 * att[4] + s2 * att[7]) * (1.f / 3.f);
        float a2 = (s0 * att[2] + s1 * att[5] + s2 * att[8]) * (1.f / 3.f);
        float mx = fmaxf(a0, fmaxf(a1, a2));
        float e0 = __expf(a0 - mx), e1 = __expf(a1 - mx), e2 = __expf(a2 - mx);
        float inv = 3.f / (e0 + e1 + e2);
        wgt[row][0] = e0 * inv;
        wgt[row][1] = e1 * inv;
        wgt[row][2] = e2 * inv;
    }
    __syncthreads();

#pragma unroll
    for (int mt = 0; mt < 2; ++mt)
#pragma unroll
        for (int kk = 0; kk < KPG; ++kk)
#pragma unroll
            for (int r = 0; r < 4; ++r) {
                int row_local = mt * 16 + lq * 4 + r;
                int row = m0 + row_local;
                if (row < n) {
                    int col = w * 16 + kk * 64 + ln15;
                    float w0 = wgt[row_local][0], w1 = wgt[row_local][1], w2 = wgt[row_local][2];
                    float ol = fmaxf(acc[mt][0 * KPG + kk][r], 0.f);
                    float oh = fmaxf(acc[mt][1 * KPG + kk][r], 0.f);
                    float om = fmaxf(acc[mt][2 * KPG + kk][r], 0.f);
                    float val = w0 * ol + w1 * oh + w2 * om;
                    if (L1)
                        feaOut[(size_t)row * HOUT + col] = f2bf(fmaxf(val, 0.f));
                    else
                        fOut[(size_t)row * HOUT + col] = val;
                }
            }
}

extern "C" void kernel_launch(void* const* d_in, const int* in_sizes, int n_in,
                              void* d_out, int out_size, void* d_ws, size_t ws_size,
                              hipStream_t stream) {
    const int F = 128;
    int n = in_sizes[0] / F;
    int e = in_sizes[1] / 2;
    const float* x = (const float*)d_in[0];
    const int* ei = (const int*)d_in[1];
    const int* erow = ei;
    const int* ecol = ei + e;
    const float *Wl1 = (const float*)d_in[2], *Wh1 = (const float*)d_in[3], *Wm1 = (const float*)d_in[4];
    const float *vl1 = (const float*)d_in[5], *vh1 = (const float*)d_in[6], *vm1 = (const float*)d_in[7];
    const float* att1 = (const float*)d_in[8];
    const float *Wl2 = (const float*)d_in[9], *Wh2 = (const float*)d_in[10], *Wm2 = (const float*)d_in[11];
    const float *vl2 = (const float*)d_in[12], *vh2 = (const float*)d_in[13], *vm2 = (const float*)d_in[14];
    const float* att2 = (const float*)d_in[15];
    float* out = (float*)d_out;

    char* ws = (char*)d_ws;
    size_t off = 0;
    auto alloc = [&](size_t b) -> void* {
        void* p = ws + off;
        off = (off + b + 255) & ~(size_t)255;
        return p;
    };
    int* deg = (int*)alloc((size_t)n * 4);          // also reused as fill cursor
    int* row_ptr = (int*)alloc((size_t)(n + 1) * 4);
    float* inv_deg = (float*)alloc((size_t)n * 4);
    int* bsum = (int*)alloc(1024);
    int* boff = (int*)alloc(1024);
    int* cols = (int*)alloc((size_t)e * 4);
    u16* S = (u16*)alloc((size_t)n * 128 * 2);
    u16* D = (u16*)alloc((size_t)n * 128 * 2);
    u16* Xb = (u16*)alloc((size_t)n * 128 * 2);
    u16* fea = (u16*)alloc((size_t)n * 128 * 2);
    u16* Wt1 = (u16*)alloc((size_t)3 * 128 * 128 * 2);
    u16* Wt2 = (u16*)alloc((size_t)3 * 64 * 128 * 2);
    (void)ws_size; (void)n_in; (void)out_size;

    const int tb = 256;
    k_cast<<<2048, 256, 0, stream>>>((const float4*)x, (u32*)Xb, (long)n * 32);
    k_prepW<<<dim3(16, 6), 256, 0, stream>>>(Wl1, Wh1, Wm1, Wl2, Wh2, Wm2, Wt1, Wt2);

    hipMemsetAsync(deg, 0, (size_t)n * 4, stream);
    k_deg<<<(e + tb - 1) / tb, tb, 0, stream>>>(erow, e, deg);
    int nb = (n + 1023) / 1024;
    k_scan_a<<<nb, 256, 0, stream>>>(deg, n, bsum);
    k_scan_b<<<1, 256, 0, stream>>>(bsum, nb, boff);
    k_scan_c<<<nb, 256, 0, stream>>>(deg, n, boff, row_ptr, inv_deg);
    hipMemsetAsync(deg, 0, (size_t)n * 4, stream);
    k_fill<<<(e + tb - 1) / tb, tb, 0, stream>>>(erow, ecol, e, row_ptr, deg, cols);

    int wb = (n + 3) / 4;  // one wave per row, 4 waves/block
    int gb = (n + 31) / 32;

    // layer 1
    k_spmm<<<wb, 256, 0, stream>>>((const u32*)Xb, row_ptr, cols, inv_deg, (u32*)S, (u32*)D, n);
    k_gemm_comb<128, true><<<gb, 256, 0, stream>>>(S, D, Xb, Wt1, vl1, vh1, vm1, att1, n, fea, nullptr);

    // layer 2
    k_spmm<<<wb, 256, 0, stream>>>((const u32*)fea, row_ptr, cols, inv_deg, (u32*)S, (u32*)D, n);
    k_gemm_comb<64, false><<<gb, 256, 0, stream>>>(S, D, fea, Wt2, vl2, vh2, vm2, att2, n, nullptr, out);
}

// Round 5
// 537.665 us; speedup vs baseline: 1.1999x; 1.0147x over previous
//
#include <hip/hip_runtime.h>

typedef unsigned short u16;
typedef unsigned int u32;
typedef __attribute__((ext_vector_type(8))) short short8;
typedef __attribute__((ext_vector_type(4))) float f32x4;

__device__ __forceinline__ float bf2f(u32 u) {
    union { u32 i; float f; } v; v.i = u << 16; return v.f;
}
__device__ __forceinline__ u16 f2bf(float f) {
    union { float f; u32 i; } v; v.f = f;
    u32 u = (v.i + 0x7fffu + ((v.i >> 16) & 1u)) >> 16;
    return (u16)u;
}

// ---------------- cast x (fp32) -> Xb (packed bf16 pairs, row-major) ----------------
__global__ void k_cast(const float4* __restrict__ X, u32* __restrict__ Xb, long total4) {
    long i = (long)blockIdx.x * blockDim.x + threadIdx.x;
    long stride = (long)gridDim.x * blockDim.x;
    for (; i < total4; i += stride) {
        float4 p = X[i];
        Xb[i * 2 + 0] = (u32)f2bf(p.x) | ((u32)f2bf(p.y) << 16);
        Xb[i * 2 + 1] = (u32)f2bf(p.z) | ((u32)f2bf(p.w) << 16);
    }
}

// ---------------- prep weights: fp32 [128 x Hout] row-major -> bf16 MFMA-B-fragment packed ----------------
// Packed layout per matrix: u16 idx = (T*4 + c)*512 + lane*8 + j  where col = T*16 + (lane&15),
// k = c*32 + (lane>>4)*8 + j.  One wave-load of 1KB = one B fragment (16 cols x 32 k).
__global__ void k_prepW(const float* __restrict__ W0, const float* __restrict__ W1,
                        const float* __restrict__ W2, const float* __restrict__ W3,
                        const float* __restrict__ W4, const float* __restrict__ W5,
                        u16* __restrict__ Wp1, u16* __restrict__ Wp2) {
    int m = blockIdx.y;
    const float* W = (m == 0) ? W0 : (m == 1) ? W1 : (m == 2) ? W2 : (m == 3) ? W3 : (m == 4) ? W4 : W5;
    int Hout = (m < 3) ? 128 : 64;
    u16* dst = (m < 3) ? (Wp1 + m * 128 * 128) : (Wp2 + (m - 3) * 64 * 128);
    int total = 128 * Hout;
    for (int i = blockIdx.x * blockDim.x + threadIdx.x; i < total; i += gridDim.x * blockDim.x) {
        int T = i / 2048;
        int c = (i / 512) & 3;
        int lane = (i / 8) & 63;
        int j = i & 7;
        int col = T * 16 + (lane & 15);
        int k = c * 32 + (lane >> 4) * 8 + j;
        dst[i] = f2bf(W[k * Hout + col]);
    }
}

// ---------------- CSR build ----------------
__global__ void k_deg(const int* __restrict__ erow, int e, int* __restrict__ deg) {
    int i = blockIdx.x * blockDim.x + threadIdx.x;
    if (i < e) atomicAdd(&deg[erow[i]], 1);
}

__global__ void k_scan_a(const int* __restrict__ deg, int n, int* __restrict__ bsum) {
    __shared__ int lds[256];
    int b = blockIdx.x, t = threadIdx.x;
    int base = b * 1024;
    int s = 0;
    for (int i = t; i < 1024; i += 256) { int idx = base + i; if (idx < n) s += deg[idx]; }
    lds[t] = s; __syncthreads();
    for (int off = 128; off > 0; off >>= 1) { if (t < off) lds[t] += lds[t + off]; __syncthreads(); }
    if (t == 0) bsum[b] = lds[0];
}

__global__ void k_scan_b(const int* __restrict__ bsum, int nb, int* __restrict__ boff) {
    __shared__ int lds[256];
    int t = threadIdx.x;
    int v = (t < nb) ? bsum[t] : 0;
    lds[t] = v; __syncthreads();
    for (int off = 1; off < 256; off <<= 1) {
        int x = (t >= off) ? lds[t - off] : 0;
        __syncthreads();
        lds[t] += x;
        __syncthreads();
    }
    if (t < nb) boff[t] = lds[t] - v;
}

__global__ void k_scan_c(const int* __restrict__ deg, int n, const int* __restrict__ boff,
                         int* __restrict__ row_ptr, float* __restrict__ inv_deg) {
    __shared__ int lds[256];
    int b = blockIdx.x, t = threadIdx.x;
    int base = b * 1024 + t * 4;
    int v0 = 0, v1 = 0, v2 = 0, v3 = 0;
    if (base + 0 < n) v0 = deg[base + 0];
    if (base + 1 < n) v1 = deg[base + 1];
    if (base + 2 < n) v2 = deg[base + 2];
    if (base + 3 < n) v3 = deg[base + 3];
    int s = v0 + v1 + v2 + v3;
    lds[t] = s; __syncthreads();
    for (int off = 1; off < 256; off <<= 1) {
        int x = (t >= off) ? lds[t - off] : 0;
        __syncthreads();
        lds[t] += x;
        __syncthreads();
    }
    int run = boff[b] + lds[t] - s;
    if (base + 0 < n) { row_ptr[base + 0] = run; inv_deg[base + 0] = v0 > 0 ? 1.f / v0 : 0.f; run += v0; }
    if (base + 1 < n) { row_ptr[base + 1] = run; inv_deg[base + 1] = v1 > 0 ? 1.f / v1 : 0.f; run += v1; }
    if (base + 2 < n) { row_ptr[base + 2] = run; inv_deg[base + 2] = v2 > 0 ? 1.f / v2 : 0.f; run += v2; }
    if (base + 3 < n) { row_ptr[base + 3] = run; inv_deg[base + 3] = v3 > 0 ? 1.f / v3 : 0.f; run += v3; }
    if (b == gridDim.x - 1 && t == 255) row_ptr[n] = run;
}

__global__ void k_fill(const int* __restrict__ erow, const int* __restrict__ ecol, int e,
                       const int* __restrict__ row_ptr, int* __restrict__ cursor, int* __restrict__ cols) {
    int i = blockIdx.x * blockDim.x + threadIdx.x;
    if (i < e) {
        int r = erow[i];
        int p = row_ptr[r] + atomicAdd(&cursor[r], 1);
        cols[p] = ecol[i];
    }
}

// ---------------- SpMM: bf16 X row-major in; A-fragment-packed S, D, X out ----------------
// Packed layout: u32 idx = R*1024 + c*256 + lane*4 + j' where for row = R*16+r, k-pair l (=lane):
// c = l/16, q = (l%16)/4, j = l%4  -> dst u32 = R*1024 + c*256 + q*64 + r*4 + j.
__global__ void k_spmm(const u32* __restrict__ X2, const int* __restrict__ row_ptr,
                       const int* __restrict__ cols, const float* __restrict__ inv_deg,
                       u32* __restrict__ Sp, u32* __restrict__ Dp, u32* __restrict__ Xp, int n) {
    int w = (int)((blockIdx.x * blockDim.x + threadIdx.x) >> 6);
    if (w >= n) return;
    int lane = threadIdx.x & 63;
    int beg = row_ptr[w], end = row_ptr[w + 1];
    float a0 = 0.f, a1 = 0.f;
    for (int j0 = beg; j0 < end; j0 += 64) {
        int cnt = end - j0; if (cnt > 64) cnt = 64;
        int myc = (lane < cnt) ? cols[j0 + lane] : 0;
        int j = 0;
        for (; j + 4 <= cnt; j += 4) {
            int c0 = __shfl(myc, j + 0);
            int c1 = __shfl(myc, j + 1);
            int c2 = __shfl(myc, j + 2);
            int c3 = __shfl(myc, j + 3);
            u32 p0 = X2[(size_t)c0 * 64 + lane];
            u32 p1 = X2[(size_t)c1 * 64 + lane];
            u32 p2 = X2[(size_t)c2 * 64 + lane];
            u32 p3 = X2[(size_t)c3 * 64 + lane];
            a0 += bf2f(p0 & 0xffffu) + bf2f(p1 & 0xffffu) + bf2f(p2 & 0xffffu) + bf2f(p3 & 0xffffu);
            a1 += bf2f(p0 >> 16) + bf2f(p1 >> 16) + bf2f(p2 >> 16) + bf2f(p3 >> 16);
        }
        for (; j < cnt; ++j) {
            int c = __shfl(myc, j);
            u32 p = X2[(size_t)c * 64 + lane];
            a0 += bf2f(p & 0xffffu);
            a1 += bf2f(p >> 16);
        }
    }
    float s = inv_deg[w];
    a0 *= s; a1 *= s;
    u32 px = X2[(size_t)w * 64 + lane];
    float x0 = bf2f(px & 0xffffu), x1 = bf2f(px >> 16);
    int cc = lane >> 4, qq = (lane >> 2) & 3, jj = lane & 3;
    size_t dst = (size_t)(w >> 4) * 1024 + cc * 256 + qq * 64 + (w & 15) * 4 + jj;
    Sp[dst] = (u32)f2bf(a0) | ((u32)f2bf(a1) << 16);
    Dp[dst] = (u32)f2bf(x0 - a0) | ((u32)f2bf(x1 - a1) << 16);
    Xp[dst] = px;
}

// ---------------- fused GEMM + attention combine, fragment-packed operands ----------------
// Block: 256 thr (4 waves), MT=64 rows. Wave w owns col-tiles col = w*16 + kk*64 for each group.
// All A/W loads are 1KB fully-coalesced global_load_dwordx4 (fragment-packed). No LDS for operands.
template<int HOUT, bool L1>
__global__ __launch_bounds__(256)
void k_gemm_comb(const u16* __restrict__ Ap0, const u16* __restrict__ Ap1, const u16* __restrict__ Ap2,
                 const u16* __restrict__ Wp,   // packed [3][HOUT/16][4][512]
                 const float* __restrict__ vl, const float* __restrict__ vh, const float* __restrict__ vm,
                 const float* __restrict__ att, int n,
                 u16* __restrict__ feaOut, float* __restrict__ fOut) {
    constexpr int KPG = HOUT / 64;   // col-slots per group per wave (2 for 128, 1 for 64)
    constexpr int NTw = 3 * KPG;
    int w = threadIdx.x >> 6, lane = threadIdx.x & 63;
    int ln15 = lane & 15, lq = lane >> 4;
    int m0 = blockIdx.x * 64;

    f32x4 acc[4][NTw];
#pragma unroll
    for (int mt = 0; mt < 4; ++mt)
#pragma unroll
        for (int k = 0; k < NTw; ++k) { f32x4 z = {0.f, 0.f, 0.f, 0.f}; acc[mt][k] = z; }

    for (int c = 0; c < 4; ++c) {
        short8 bfr[NTw];
#pragma unroll
        for (int k = 0; k < NTw; ++k) {
            int g = k / KPG, kk = k % KPG;
            int Tl = w + kk * 4;
            bfr[k] = *(const short8*)(Wp + (size_t)g * (HOUT * 128) + (Tl * 4 + c) * 512 + lane * 8);
        }
#pragma unroll
        for (int mt = 0; mt < 4; ++mt) {
            size_t off = ((size_t)((m0 >> 4) + mt) * 4 + c) * 512 + lane * 8;
            short8 a0 = *(const short8*)(Ap0 + off);
            short8 a1 = *(const short8*)(Ap1 + off);
            short8 a2 = *(const short8*)(Ap2 + off);
#pragma unroll
            for (int k = 0; k < NTw; ++k) {
                int g = k / KPG;
                short8 av = (g == 0) ? a0 : ((g == 1) ? a1 : a2);
                acc[mt][k] = __builtin_amdgcn_mfma_f32_16x16x32_bf16(av, bfr[k], acc[mt][k], 0, 0, 0);
            }
        }
    }

    // per-lane v values for owned cols
    float vval[NTw];
#pragma unroll
    for (int k = 0; k < NTw; ++k) {
        int g = k / KPG, kk = k % KPG;
        int col = w * 16 + kk * 64 + ln15;
        vval[k] = (g == 0 ? vl : (g == 1 ? vh : vm))[col];
    }

    __shared__ float part[4][3][64];
    __shared__ float wgt[64][3];
#pragma unroll
    for (int mt = 0; mt < 4; ++mt) {
        float pdg[3][4];
#pragma unroll
        for (int g = 0; g < 3; ++g)
#pragma unroll
            for (int r = 0; r < 4; ++r) pdg[g][r] = 0.f;
#pragma unroll
        for (int k = 0; k < NTw; ++k) {
            int g = k / KPG;
#pragma unroll
            for (int r = 0; r < 4; ++r)
                pdg[g][r] += fmaxf(acc[mt][k][r], 0.f) * vval[k];
        }
#pragma unroll
        for (int off = 1; off < 16; off <<= 1)
#pragma unroll
            for (int g = 0; g < 3; ++g)
#pragma unroll
                for (int r = 0; r < 4; ++r)
                    pdg[g][r] += __shfl_xor(pdg[g][r], off);
        if (ln15 == 0) {
#pragma unroll
            for (int g = 0; g < 3; ++g)
#pragma unroll
                for (int r = 0; r < 4; ++r)
                    part[w][g][mt * 16 + lq * 4 + r] = pdg[g][r];
        }
    }
    __syncthreads();
    if (threadIdx.x < 64) {
        int row = threadIdx.x;
        float d0 = part[0][0][row] + part[1][0][row] + part[2][0][row] + part[3][0][row];
        float d1 = part[0][1][row] + part[1][1][row] + part[2][1][row] + part[3][1][row];
        float d2 = part[0][2][row] + part[1][2][row] + part[2][2][row] + part[3][2][row];
        float s0 = 1.f / (1.f + __expf(-d0));
        float s1 = 1.f / (1.f + __expf(-d1));
        float s2 = 1.f / (1.f + __expf(-d2));
        float a0 = (s0 * att[0] + s1 * att[3] + s2 * att[6]) * (1.f / 3.f);
        float a1 = (s0 * att[1] + s1 * att[4] + s2 * att[7]) * (1.f / 3.f);
        float a2 = (s0 * att[2] + s1 * att[5] + s2 * att[8]) * (1.f / 3.f);
        float mx = fmaxf(a0, fmaxf(a1, a2));
        float e0 = __expf(a0 - mx), e1 = __expf(a1 - mx), e2 = __expf(a2 - mx);
        float inv = 3.f / (e0 + e1 + e2);
        wgt[row][0] = e0 * inv;
        wgt[row][1] = e1 * inv;
        wgt[row][2] = e2 * inv;
    }
    __syncthreads();

#pragma unroll
    for (int mt = 0; mt < 4; ++mt)
#pragma unroll
        for (int kk = 0; kk < KPG; ++kk)
#pragma unroll
            for (int r = 0; r < 4; ++r) {
                int row_local = mt * 16 + lq * 4 + r;
                int row = m0 + row_local;
                if (row < n) {
                    int col = w * 16 + kk * 64 + ln15;
                    float w0 = wgt[row_local][0], w1 = wgt[row_local][1], w2 = wgt[row_local][2];
                    float ol = fmaxf(acc[mt][0 * KPG + kk][r], 0.f);
                    float oh = fmaxf(acc[mt][1 * KPG + kk][r], 0.f);
                    float om = fmaxf(acc[mt][2 * KPG + kk][r], 0.f);
                    float val = w0 * ol + w1 * oh + w2 * om;
                    if (L1)
                        feaOut[(size_t)row * HOUT + col] = f2bf(fmaxf(val, 0.f));
                    else
                        fOut[(size_t)row * HOUT + col] = val;
                }
            }
}

extern "C" void kernel_launch(void* const* d_in, const int* in_sizes, int n_in,
                              void* d_out, int out_size, void* d_ws, size_t ws_size,
                              hipStream_t stream) {
    const int F = 128;
    int n = in_sizes[0] / F;
    int e = in_sizes[1] / 2;
    int n64 = (n + 63) & ~63;
    const float* x = (const float*)d_in[0];
    const int* ei = (const int*)d_in[1];
    const int* erow = ei;
    const int* ecol = ei + e;
    const float *Wl1 = (const float*)d_in[2], *Wh1 = (const float*)d_in[3], *Wm1 = (const float*)d_in[4];
    const float *vl1 = (const float*)d_in[5], *vh1 = (const float*)d_in[6], *vm1 = (const float*)d_in[7];
    const float* att1 = (const float*)d_in[8];
    const float *Wl2 = (const float*)d_in[9], *Wh2 = (const float*)d_in[10], *Wm2 = (const float*)d_in[11];
    const float *vl2 = (const float*)d_in[12], *vh2 = (const float*)d_in[13], *vm2 = (const float*)d_in[14];
    const float* att2 = (const float*)d_in[15];
    float* out = (float*)d_out;

    char* ws = (char*)d_ws;
    size_t off = 0;
    auto alloc = [&](size_t b) -> void* {
        void* p = ws + off;
        off = (off + b + 255) & ~(size_t)255;
        return p;
    };
    int* deg = (int*)alloc((size_t)n * 4);          // also reused as fill cursor
    int* row_ptr = (int*)alloc((size_t)(n + 1) * 4);
    float* inv_deg = (float*)alloc((size_t)n * 4);
    int* bsum = (int*)alloc(1024);
    int* boff = (int*)alloc(1024);
    int* cols = (int*)alloc((size_t)e * 4);
    u32* Sp = (u32*)alloc((size_t)n64 * 64 * 4);
    u32* Dp = (u32*)alloc((size_t)n64 * 64 * 4);
    u32* Xp = (u32*)alloc((size_t)n64 * 64 * 4);
    u32* Fp = (u32*)alloc((size_t)n64 * 64 * 4);
    u16* Xb = (u16*)alloc((size_t)n * 128 * 2);
    u16* fea = (u16*)alloc((size_t)n * 128 * 2);
    u16* Wp1 = (u16*)alloc((size_t)3 * 128 * 128 * 2);
    u16* Wp2 = (u16*)alloc((size_t)3 * 64 * 128 * 2);
    (void)ws_size; (void)n_in; (void)out_size;

    const int tb = 256;
    k_cast<<<2048, 256, 0, stream>>>((const float4*)x, (u32*)Xb, (long)n * 32);
    k_prepW<<<dim3(16, 6), 256, 0, stream>>>(Wl1, Wh1, Wm1, Wl2, Wh2, Wm2, Wp1, Wp2);

    hipMemsetAsync(deg, 0, (size_t)n * 4, stream);
    k_deg<<<(e + tb - 1) / tb, tb, 0, stream>>>(erow, e, deg);
    int nb = (n + 1023) / 1024;
    k_scan_a<<<nb, 256, 0, stream>>>(deg, n, bsum);
    k_scan_b<<<1, 256, 0, stream>>>(bsum, nb, boff);
    k_scan_c<<<nb, 256, 0, stream>>>(deg, n, boff, row_ptr, inv_deg);
    hipMemsetAsync(deg, 0, (size_t)n * 4, stream);
    k_fill<<<(e + tb - 1) / tb, tb, 0, stream>>>(erow, ecol, e, row_ptr, deg, cols);

    int wb = (n + 3) / 4;  // one wave per row, 4 waves/block
    int gb = n64 / 64;

    // layer 1
    k_spmm<<<wb, 256, 0, stream>>>((const u32*)Xb, row_ptr, cols, inv_deg, Sp, Dp, Xp, n);
    k_gemm_comb<128, true><<<gb, 256, 0, stream>>>((const u16*)Sp, (const u16*)Dp, (const u16*)Xp,
                                                   Wp1, vl1, vh1, vm1, att1, n, fea, nullptr);

    // layer 2
    k_spmm<<<wb, 256, 0, stream>>>((const u32*)fea, row_ptr, cols, inv_deg, Sp, Dp, Fp, n);
    k_gemm_comb<64, false><<<gb, 256, 0, stream>>>((const u16*)Sp, (const u16*)Dp, (const u16*)Fp,
                                                   Wp2, vl2, vh2, vm2, att2, n, nullptr, out);
}